// Round 4
// baseline (762.591 us; speedup 1.0000x reference)
//
#include <hip/hip_runtime.h>

// SSIM3D loss, fused separable 11^3 Gaussian conv of 5 fields + SSIM map + mean.
// Round 4 (round 3 never ran): b128 LDS everywhere; wbA stride 17 float4
// (uniform banks for W-writes/H-reads); H-conv 2-wide on 256 threads (12 taps
// for 2 output rows) with xfer buffer back to ring owners; slice commit +
// global prefetch co-scheduled with H-conv. 2 barriers/slice.

#define DD 128
#define HH 256
#define WW 256
#define TH 32
#define TW 16
#define DC 32
#define SLICES (DC + 10)      // 42
#define KS 11
#define XH 42                 // staged rows
#define XSTR 52               // xt/yt row stride (floats): 20r mod 32 -> 2-way only
#define WBAS 17               // wbA row stride (float4): uniform write/read banks
#define WBBS 16               // wbB row stride (floats): 2-way reads (free)
#define NTH 512
#define PLANE 65536
#define C1F 1.0e-4f
#define C2F 9.0e-4f
#define NVOX (2.0 * 128.0 * 256.0 * 256.0)

// init: zero accumulator, extract separable g[11] (row sums of the 11^3 window)
__global__ void ssim_init_kernel(const float* __restrict__ win,
                                 double* __restrict__ acc,
                                 float* __restrict__ g) {
    int i = threadIdx.x;
    if (i == 0) acc[0] = 0.0;
    if (i < KS) {
        float s = 0.f;
        #pragma unroll 1
        for (int j = 0; j < KS * KS; ++j) s += win[i * KS * KS + j];
        g[i] = s;
    }
}

__global__ __launch_bounds__(NTH, 4)
void ssim_main_kernel(const float* __restrict__ img1,
                      const float* __restrict__ img2,
                      const float* __restrict__ gcoef,
                      double* __restrict__ acc) {
    __shared__ __align__(16) float xt[XH * XSTR];
    __shared__ __align__(16) float yt[XH * XSTR];
    __shared__ float4 wbA[XH * WBAS];            // fields x, y, xx, yy
    __shared__ __align__(16) float wbB[XH * WBBS]; // field xy
    __shared__ float4 xfA[TH * TW];              // H-conv results s0..s3
    __shared__ float  xfB[TH * TW];              // H-conv result s4
    __shared__ double red[NTH / 64];

    const int tid = threadIdx.x;
    const int tx = tid & 15;
    const int ty = tid >> 4;              // 0..31
    const int w0 = blockIdx.x * TW;
    const int h0 = blockIdx.y * TH;
    const int b  = blockIdx.z >> 2;
    const int d0 = (blockIdx.z & 3) * DC;

    const float* base1 = img1 + (size_t)b * (DD * PLANE);
    const float* base2 = img2 + (size_t)b * (DD * PLANE);

    // ---- staging geometry: 336 tasks = 42 rows x 8 aligned float4 cols ----
    // xt col c holds gw = w0 - 8 + c, c in [0,32)
    const int sr = tid >> 3;
    const int sc = (tid & 7) << 2;
    const int gh = h0 - 5 + sr;
    const int gw = w0 - 8 + sc;
    const bool sOk = (tid < 336) && ((unsigned)gh < HH) && ((unsigned)gw < WW);
    const int gOfs = sOk ? (gh * WW + gw) : 0;
    const int lOfs = sr * XSTR + sc;

    float G[KS];
    #pragma unroll
    for (int i = 0; i < KS; ++i) G[i] = gcoef[i];

    float ring[5][KS];
    #pragma unroll
    for (int f = 0; f < 5; ++f)
        #pragma unroll
        for (int i = 0; i < KS; ++i) ring[f][i] = 0.f;

    const float4 z4 = make_float4(0.f, 0.f, 0.f, 0.f);
    float4 pA = z4, pB = z4;

    // ---- prologue: commit slice (d0-5), prefetch slice (d0-4) ----
    {
        int dIn = d0 - 5;
        if (sOk && (unsigned)dIn < DD) {
            pA = *(const float4*)(base1 + dIn * PLANE + gOfs);
            pB = *(const float4*)(base2 + dIn * PLANE + gOfs);
        }
    }
    if (tid < 336) {
        *(float4*)&xt[lOfs] = pA;
        *(float4*)&yt[lOfs] = pB;
    }
    {
        int dIn = d0 - 4;
        pA = z4; pB = z4;
        if (sOk && (unsigned)dIn < DD) {
            pA = *(const float4*)(base1 + dIn * PLANE + gOfs);
            pB = *(const float4*)(base2 + dIn * PLANE + gOfs);
        }
    }
    __syncthreads();

    double lsum = 0.0;

    for (int s = 0; s < SLICES; ++s) {
        // ---- phase 1: W-conv, 168 tasks x 4 outputs (reads xt/yt -> wb) ----
        if (tid < 168) {
            const int r = tid >> 2, q = tid & 3;
            const float* xp = &xt[r * XSTR + (q << 2)];
            const float* yp = &yt[r * XSTR + (q << 2)];
            float a0[4] = {0,0,0,0}, a1[4] = {0,0,0,0}, a2[4] = {0,0,0,0},
                  a3[4] = {0,0,0,0}, a4[4] = {0,0,0,0};
            #pragma unroll
            for (int bdx = 0; bdx < 5; ++bdx) {
                float4 xv4 = *(const float4*)(xp + (bdx << 2));
                float4 yv4 = *(const float4*)(yp + (bdx << 2));
                #pragma unroll
                for (int i = 0; i < 4; ++i) {
                    const int c = bdx * 4 + i;          // flat staged col rel. to 4q
                    if (c < 3 || c > 16) continue;      // taps cover cols j+k+3
                    const float xv = (i == 0) ? xv4.x : (i == 1) ? xv4.y : (i == 2) ? xv4.z : xv4.w;
                    const float yv = (i == 0) ? yv4.x : (i == 1) ? yv4.y : (i == 2) ? yv4.z : yv4.w;
                    #pragma unroll
                    for (int j = 0; j < 4; ++j) {
                        const int k = c - 3 - j;
                        if (k < 0 || k >= KS) continue;
                        const float t1 = G[k] * xv;
                        const float t2 = G[k] * yv;
                        a0[j] += t1;
                        a1[j] += t2;
                        a2[j] = fmaf(t1, xv, a2[j]);
                        a3[j] = fmaf(t2, yv, a3[j]);
                        a4[j] = fmaf(t1, yv, a4[j]);
                    }
                }
            }
            #pragma unroll
            for (int j = 0; j < 4; ++j)
                wbA[r * WBAS + (q << 2) + j] = make_float4(a0[j], a1[j], a2[j], a3[j]);
            *(float4*)&wbB[r * WBBS + (q << 2)] = make_float4(a4[0], a4[1], a4[2], a4[3]);
        }
        __syncthreads();   // wb ready; xt readers done

        // ---- phase 2: commit next slice + issue prefetch + H-conv ----
        if (s + 1 < SLICES) {
            if (tid < 336) {
                *(float4*)&xt[lOfs] = pA;
                *(float4*)&yt[lOfs] = pB;
            }
        }
        {
            int dIn = d0 - 3 + s;                 // slice s+2 of the stream
            pA = z4; pB = z4;
            if (sOk && ((unsigned)dIn < DD) && (s + 2 < SLICES)) {
                pA = *(const float4*)(base1 + dIn * PLANE + gOfs);
                pB = *(const float4*)(base2 + dIn * PLANE + gOfs);
            }
        }
        if (tid < 256) {
            // 2-wide H-conv: output rows 2m, 2m+1 at col cx; 12 shared taps
            const int m2 = tid >> 4;              // 0..15
            const int cx = tid & 15;
            float b0 = 0.f, b1 = 0.f, b2 = 0.f, b3 = 0.f, b4 = 0.f;
            float c0 = 0.f, c1 = 0.f, c2 = 0.f, c3 = 0.f, c4 = 0.f;
            #pragma unroll
            for (int j = 0; j < KS + 1; ++j) {
                float4 A = wbA[(2 * m2 + j) * WBAS + cx];
                float  B = wbB[(2 * m2 + j) * WBBS + cx];
                if (j < KS) {
                    const float gk = G[j];
                    b0 = fmaf(gk, A.x, b0); b1 = fmaf(gk, A.y, b1);
                    b2 = fmaf(gk, A.z, b2); b3 = fmaf(gk, A.w, b3);
                    b4 = fmaf(gk, B,   b4);
                }
                if (j >= 1) {
                    const float gk = G[j - 1];
                    c0 = fmaf(gk, A.x, c0); c1 = fmaf(gk, A.y, c1);
                    c2 = fmaf(gk, A.z, c2); c3 = fmaf(gk, A.w, c3);
                    c4 = fmaf(gk, B,   c4);
                }
            }
            const int o0 = (2 * m2) * TW + cx;
            xfA[o0]      = make_float4(b0, b1, b2, b3);
            xfB[o0]      = b4;
            xfA[o0 + TW] = make_float4(c0, c1, c2, c3);
            xfB[o0 + TW] = c4;
        }
        __syncthreads();   // xfer ready; xt commit complete

        // ---- phase 3: ring push + emit (all 512 threads, own voxel) ----
        #pragma unroll
        for (int f = 0; f < 5; ++f)
            #pragma unroll
            for (int i = 0; i < KS - 1; ++i) ring[f][i] = ring[f][i + 1];
        {
            const float4 S = xfA[ty * TW + tx];
            const float s4v = xfB[ty * TW + tx];
            ring[0][KS-1] = S.x; ring[1][KS-1] = S.y; ring[2][KS-1] = S.z;
            ring[3][KS-1] = S.w; ring[4][KS-1] = s4v;
        }
        if (s >= 10) {
            float m1 = 0.f, m2 = 0.f, exx = 0.f, eyy = 0.f, exy = 0.f;
            #pragma unroll
            for (int i = 0; i < KS; ++i) {
                const float gi = G[i];
                m1  = fmaf(gi, ring[0][i], m1);
                m2  = fmaf(gi, ring[1][i], m2);
                exx = fmaf(gi, ring[2][i], exx);
                eyy = fmaf(gi, ring[3][i], eyy);
                exy = fmaf(gi, ring[4][i], exy);
            }
            const float mu11 = m1 * m1, mu22 = m2 * m2, mu12 = m1 * m2;
            const float sg1  = exx - mu11;
            const float sg2  = eyy - mu22;
            const float sg12 = exy - mu12;
            const float num = (2.f * mu12 + C1F) * (2.f * sg12 + C2F);
            const float den = (mu11 + mu22 + C1F) * (sg1 + sg2 + C2F);
            lsum += (double)(num / den);
        }
    }

    // block reduction -> one f64 atomic
    #pragma unroll
    for (int off = 32; off > 0; off >>= 1)
        lsum += __shfl_down(lsum, off, 64);
    const int lane = tid & 63, wid = tid >> 6;
    if (lane == 0) red[wid] = lsum;
    __syncthreads();
    if (tid == 0) {
        double bsum = 0.0;
        #pragma unroll
        for (int wv = 0; wv < NTH / 64; ++wv) bsum += red[wv];
        atomicAdd(acc, bsum);
    }
}

__global__ void ssim_fin_kernel(const double* __restrict__ acc,
                                float* __restrict__ out) {
    out[0] = (float)(1.0 - acc[0] / NVOX);
}

extern "C" void kernel_launch(void* const* d_in, const int* in_sizes, int n_in,
                              void* d_out, int out_size, void* d_ws, size_t ws_size,
                              hipStream_t stream) {
    const float* img1 = (const float*)d_in[0];
    const float* img2 = (const float*)d_in[1];
    const float* win  = (const float*)d_in[2];
    double* acc = (double*)d_ws;
    float*  g   = (float*)((char*)d_ws + 16);

    hipLaunchKernelGGL(ssim_init_kernel, dim3(1), dim3(64), 0, stream, win, acc, g);
    hipLaunchKernelGGL(ssim_main_kernel, dim3(WW / TW, HH / TH, 2 * (DD / DC)),
                       dim3(NTH), 0, stream, img1, img2, g, acc);
    hipLaunchKernelGGL(ssim_fin_kernel, dim3(1), dim3(1), 0, stream, acc, (float*)d_out);
}